// Round 3
// baseline (365.514 us; speedup 1.0000x reference)
//
#include <hip/hip_runtime.h>
#include <hip/hip_bf16.h>

// SoftSOM: dists = cdist(x, P); W = softmax(-dists/0.4); blended = W @ P
// N=524288 tokens, D=128, M=256 protos. Outputs: blended [N,128] f32, weights [N,256] f32.

#define N_TOK 524288
#define DIM 128
#define M_PROTO 256

typedef __attribute__((ext_vector_type(8))) short bf16x8;
typedef __attribute__((ext_vector_type(4))) float f32x4;
typedef __attribute__((ext_vector_type(4))) unsigned short us4;

static __device__ __forceinline__ unsigned short f2bf(float f) {
    unsigned int u = __float_as_uint(f);
    u += 0x7FFFu + ((u >> 16) & 1u);   // round-to-nearest-even
    return (unsigned short)(u >> 16);
}
static __device__ __forceinline__ float bf2f(unsigned short h) {
    return __uint_as_float(((unsigned int)h) << 16);
}

// ---------------------------------------------------------------------------
// Prep: P -> bf16 fragments.
//  - Cross  (S^T = P @ X^T): A-frag, SINGLE bf16 (X carries hi/lo exactness).
//      PfH[((kt*16 + mfrag)*64 + lane)*8 + j] ; kt=d>>5, mfrag=m>>4,
//      lane = ((d>>3)&3)*16 + (m&15), j = d&7.
//  - Blended (Bl = W @ P): B-frag, hi/lo split.
//      PT*[((kt2*8 + ng)*64 + lane)*8 + j] ; kt2=m>>5, ng=d>>4,
//      lane = ((m>>3)&3)*16 + (d&15), j = m&7.
// Also p_sq[256].
// ---------------------------------------------------------------------------
__global__ void __launch_bounds__(128) prep_kernel(
        const float* __restrict__ P,
        unsigned short* __restrict__ PfH,
        unsigned short* __restrict__ PTfH, unsigned short* __restrict__ PTfL,
        float* __restrict__ psq) {
    int m = blockIdx.x;      // proto 0..255
    int d = threadIdx.x;     // dim   0..127
    float v = P[m * DIM + d];
    unsigned short hi = f2bf(v);
    unsigned short lo = f2bf(v - bf2f(hi));

    // cross A-frag position (A = P, rows=proto, k=d) — hi only
    int ci = (((d >> 5) * 16 + (m >> 4)) * 64 + (((d >> 3) & 3) * 16 + (m & 15))) * 8 + (d & 7);
    PfH[ci] = hi;

    // blended B-frag position (B = P, k=m(proto), col=d) — hi/lo
    int bi = (((m >> 5) * 8 + (d >> 4)) * 64 + (((m >> 3) & 3) * 16 + (d & 15))) * 8 + (m & 7);
    PTfH[bi] = hi; PTfL[bi] = lo;

    // psq reduce over 128 threads (2 waves)
    float s = v * v;
    #pragma unroll
    for (int off = 1; off < 64; off <<= 1) s += __shfl_xor(s, off, 64);
    __shared__ float part[2];
    if ((threadIdx.x & 63) == 0) part[threadIdx.x >> 6] = s;
    __syncthreads();
    if (threadIdx.x == 0) psq[m] = part[0] + part[1];
}

// ---------------------------------------------------------------------------
// Main fused kernel: 64 tokens per block, 256 threads (4 waves, 16 tok/wave).
// No X staging: each lane loads its OWN X fragment (token w*16+c) straight
// from global, converts to bf16 hi/lo in registers, accumulates x_sq inline.
// Phase 2: S^T = P @ X^T via mfma_f32_16x16x32_bf16 (P single-bf16, X hi/lo).
// Phase 3: in-register softmax (exp2 domain, 2 shfl_xor reduces).
// Phase 4: W tile (bf16) -> LDS, barrier, coalesced f32 weight writes.
// Phase 5: blended = W @ P via MFMA (P hi/lo), 64B-chunk f32 stores.
// LDS = 34.8 KB -> 4 blocks/CU for compute/memory phase overlap.
// ---------------------------------------------------------------------------
__global__ void __launch_bounds__(256, 4) softsom_main(
        const float* __restrict__ X,
        const unsigned short* __restrict__ PfH,
        const unsigned short* __restrict__ PTfH, const unsigned short* __restrict__ PTfL,
        const float* __restrict__ psq,
        float* __restrict__ blended, float* __restrict__ weights) {

    __shared__ __align__(16) unsigned short Wl[64][264];   // 33792 B
    __shared__ float s_psq[256];

    const int t = threadIdx.x;
    const long base_tok = (long)blockIdx.x * 64;

    s_psq[t] = psq[t];
    __syncthreads();   // s_psq ready (cheap, before the long MFMA phase)

    const int w = t >> 6;          // wave 0..3
    const int l = t & 63;          // lane
    const int c = l & 15;
    const int g = l >> 4;
    const int myrow = w * 16 + c;  // this lane's token row within the tile

    const float* xrow = X + (base_tok + myrow) * DIM;

    // ---- Phase 2: cross S^T = P @ X^T (X from global, hi/lo in regs) ----
    f32x4 acc[16];
    #pragma unroll
    for (int m = 0; m < 16; ++m) acc[m] = (f32x4){0.f, 0.f, 0.f, 0.f};

    const bf16x8* pfh = (const bf16x8*)PfH;
    float ps = 0.f;

    #pragma unroll
    for (int kt = 0; kt < 4; ++kt) {
        float4 v0 = *(const float4*)(xrow + kt * 32 + g * 8);
        float4 v1 = *(const float4*)(xrow + kt * 32 + g * 8 + 4);
        float xv[8] = {v0.x, v0.y, v0.z, v0.w, v1.x, v1.y, v1.z, v1.w};
        bf16x8 bh, bl;
        #pragma unroll
        for (int j = 0; j < 8; ++j) {
            ps += xv[j] * xv[j];
            unsigned short h = f2bf(xv[j]);
            bh[j] = (short)h;
            bl[j] = (short)f2bf(xv[j] - bf2f(h));
        }
        #pragma unroll
        for (int m = 0; m < 16; ++m) {
            bf16x8 ah = pfh[(kt * 16 + m) * 64 + l];
            acc[m] = __builtin_amdgcn_mfma_f32_16x16x32_bf16(ah, bh, acc[m], 0, 0, 0);
            acc[m] = __builtin_amdgcn_mfma_f32_16x16x32_bf16(ah, bl, acc[m], 0, 0, 0);
        }
    }
    ps += __shfl_xor(ps, 16, 64);
    ps += __shfl_xor(ps, 32, 64);
    const float xq = ps;

    // ---- Phase 3: softmax over protos (exp2 domain) ----
    const float K2 = 3.6067376022224085f;  // (1/0.4) * log2(e)
    float mx = -3.4e38f;
    #pragma unroll
    for (int m = 0; m < 16; ++m) {
        #pragma unroll
        for (int r = 0; r < 4; ++r) {
            int proto = m * 16 + g * 4 + r;
            float s2 = fmaxf(xq + s_psq[proto] - 2.f * acc[m][r], 0.f);
            float lg = -sqrtf(s2) * K2;
            acc[m][r] = lg;
            mx = fmaxf(mx, lg);
        }
    }
    mx = fmaxf(mx, __shfl_xor(mx, 16, 64));
    mx = fmaxf(mx, __shfl_xor(mx, 32, 64));
    float sum = 0.f;
    #pragma unroll
    for (int m = 0; m < 16; ++m) {
        #pragma unroll
        for (int r = 0; r < 4; ++r) {
            float p = exp2f(acc[m][r] - mx);
            acc[m][r] = p;
            sum += p;
        }
    }
    sum += __shfl_xor(sum, 16, 64);
    sum += __shfl_xor(sum, 32, 64);
    const float inv = 1.0f / sum;

    // ---- Phase 4: W -> LDS (bf16), barrier, coalesced f32 weight writes ----
    #pragma unroll
    for (int m = 0; m < 16; ++m) {
        us4 wv = {f2bf(acc[m][0] * inv), f2bf(acc[m][1] * inv),
                  f2bf(acc[m][2] * inv), f2bf(acc[m][3] * inv)};
        *(us4*)&Wl[myrow][m * 16 + g * 4] = wv;
    }
    __syncthreads();

    {
        float* wout = weights + base_tok * M_PROTO;
        #pragma unroll
        for (int i = 0; i < 16; ++i) {
            int idx = i * 256 + t;
            int row = idx >> 6;
            int c4  = (idx & 63) * 4;
            us4 wv = *(const us4*)&Wl[row][c4];
            float4 o = {bf2f(wv[0]), bf2f(wv[1]), bf2f(wv[2]), bf2f(wv[3])};
            *(float4*)&wout[row * M_PROTO + c4] = o;
        }
    }

    // ---- Phase 5: blended = W @ P (K=256; wave w owns cols w*32..w*32+31) ----
    f32x4 acc2[4][2];
    #pragma unroll
    for (int m = 0; m < 4; ++m)
        #pragma unroll
        for (int n = 0; n < 2; ++n) acc2[m][n] = (f32x4){0.f, 0.f, 0.f, 0.f};

    const bf16x8* pth = (const bf16x8*)PTfH;
    const bf16x8* ptl = (const bf16x8*)PTfL;

    #pragma unroll
    for (int kt = 0; kt < 8; ++kt) {
        bf16x8 aw[4];
        #pragma unroll
        for (int m = 0; m < 4; ++m)
            aw[m] = *(const bf16x8*)&Wl[m * 16 + c][kt * 32 + g * 8];
        #pragma unroll
        for (int n = 0; n < 2; ++n) {
            int ng = w * 2 + n;
            bf16x8 bh = pth[(kt * 8 + ng) * 64 + l];
            bf16x8 bl = ptl[(kt * 8 + ng) * 64 + l];
            #pragma unroll
            for (int m = 0; m < 4; ++m) {
                acc2[m][n] = __builtin_amdgcn_mfma_f32_16x16x32_bf16(aw[m], bh, acc2[m][n], 0, 0, 0);
                acc2[m][n] = __builtin_amdgcn_mfma_f32_16x16x32_bf16(aw[m], bl, acc2[m][n], 0, 0, 0);
            }
        }
    }

    float* bout = blended + base_tok * DIM;
    #pragma unroll
    for (int m = 0; m < 4; ++m)
        #pragma unroll
        for (int n = 0; n < 2; ++n)
            #pragma unroll
            for (int r = 0; r < 4; ++r) {
                int row = m * 16 + g * 4 + r;
                int d   = w * 32 + n * 16 + c;
                bout[row * DIM + d] = acc2[m][n][r];
            }
}

extern "C" void kernel_launch(void* const* d_in, const int* in_sizes, int n_in,
                              void* d_out, int out_size, void* d_ws, size_t ws_size,
                              hipStream_t stream) {
    const float* x = (const float*)d_in[0];
    const float* protos = (const float*)d_in[1];

    float* out = (float*)d_out;
    float* blended = out;                               // [N,128]
    float* weights = out + (size_t)N_TOK * DIM;         // [N,256]

    unsigned short* PfH  = (unsigned short*)d_ws;       // 32768 elems each
    unsigned short* PTfH = PfH  + 32768;
    unsigned short* PTfL = PTfH + 32768;
    float*          psq  = (float*)(PTfL + 32768);      // 256 f32

    prep_kernel<<<M_PROTO, DIM, 0, stream>>>(protos, PfH, PTfH, PTfL, psq);
    softsom_main<<<N_TOK / 64, 256, 0, stream>>>(x, PfH, PTfH, PTfL, psq,
                                                 blended, weights);
}

// Round 4
// 276.611 us; speedup vs baseline: 1.3214x; 1.3214x over previous
//
#include <hip/hip_runtime.h>
#include <hip/hip_bf16.h>

// SoftSOM: dists = cdist(x, P); W = softmax(-dists/0.4); blended = W @ P
// N=524288 tokens, D=128, M=256 protos. Outputs: blended [N,128] f32, weights [N,256] f32.

#define N_TOK 524288
#define DIM 128
#define M_PROTO 256

typedef __attribute__((ext_vector_type(8))) short bf16x8;
typedef __attribute__((ext_vector_type(4))) float f32x4;
typedef __attribute__((ext_vector_type(4))) unsigned short us4;

typedef __attribute__((address_space(1))) const unsigned int g_u32;
typedef __attribute__((address_space(3))) unsigned int l_u32;

static __device__ __forceinline__ unsigned short f2bf(float f) {
    unsigned int u = __float_as_uint(f);
    u += 0x7FFFu + ((u >> 16) & 1u);   // round-to-nearest-even
    return (unsigned short)(u >> 16);
}
static __device__ __forceinline__ float bf2f(unsigned short h) {
    return __uint_as_float(((unsigned int)h) << 16);
}

// ---------------------------------------------------------------------------
// Prep: P -> bf16 fragments.
//  - Cross  (S^T = P @ X^T): A-frag, SINGLE bf16 (X carries hi/lo exactness).
//      PfH[((kt*16 + mfrag)*64 + lane)*8 + j] ; kt=d>>5, mfrag=m>>4,
//      lane = ((d>>3)&3)*16 + (m&15), j = d&7.   (linear order == LDS order)
//  - Blended (Bl = W @ P): B-frag, hi/lo split.
//      PT*[((kt2*8 + ng)*64 + lane)*8 + j] ; kt2=m>>5, ng=d>>4,
//      lane = ((m>>3)&3)*16 + (d&15), j = m&7.
// Also p_sq[256].
// ---------------------------------------------------------------------------
__global__ void __launch_bounds__(128) prep_kernel(
        const float* __restrict__ P,
        unsigned short* __restrict__ PfH,
        unsigned short* __restrict__ PTfH, unsigned short* __restrict__ PTfL,
        float* __restrict__ psq) {
    int m = blockIdx.x;      // proto 0..255
    int d = threadIdx.x;     // dim   0..127
    float v = P[m * DIM + d];
    unsigned short hi = f2bf(v);
    unsigned short lo = f2bf(v - bf2f(hi));

    // cross A-frag position (A = P, rows=proto, k=d) — hi only
    int ci = (((d >> 5) * 16 + (m >> 4)) * 64 + (((d >> 3) & 3) * 16 + (m & 15))) * 8 + (d & 7);
    PfH[ci] = hi;

    // blended B-frag position (B = P, k=m(proto), col=d) — hi/lo
    int bi = (((m >> 5) * 8 + (d >> 4)) * 64 + (((m >> 3) & 3) * 16 + (d & 15))) * 8 + (m & 7);
    PTfH[bi] = hi; PTfL[bi] = lo;

    // psq reduce over 128 threads (2 waves)
    float s = v * v;
    #pragma unroll
    for (int off = 1; off < 64; off <<= 1) s += __shfl_xor(s, off, 64);
    __shared__ float part[2];
    if ((threadIdx.x & 63) == 0) part[threadIdx.x >> 6] = s;
    __syncthreads();
    if (threadIdx.x == 0) psq[m] = part[0] + part[1];
}

// ---------------------------------------------------------------------------
// Main fused kernel: 128 tokens per block, 512 threads (8 waves, 16 tok/wave).
//  - X: per-lane direct global loads (token w*16+c), issued as bulk prefetch
//    at kernel top; latency hides under P staging + barrier. hi/lo in regs.
//  - PfH (64 KB): staged to LDS once per block via global_load_lds width=16
//    (linear fragment layout); cross reads are lane-linear ds_read_b128.
//    -> 8x less L2 traffic than every wave streaming PfH from L2.
//  - Wl[128][264] ALIASES the Plds region (barrier-protected).
// Phase 2: S^T = P @ X^T (P single-bf16, X hi/lo, 2 MFMA/frag).
// Phase 3: in-register softmax (lane holds 64 logits of 1 token; 2 shfl_xor).
// Phase 4: W (bf16) -> LDS; coalesced f32 weight writes.
// Phase 5: blended = W @ P via MFMA (PT hi/lo from L2 — no intra-block reuse).
// ---------------------------------------------------------------------------
__global__ void __launch_bounds__(512, 4) softsom_main(
        const float* __restrict__ X,
        const unsigned short* __restrict__ PfH,
        const unsigned short* __restrict__ PTfH, const unsigned short* __restrict__ PTfL,
        const float* __restrict__ psq,
        float* __restrict__ blended, float* __restrict__ weights) {

    __shared__ __align__(16) unsigned char smem[67584];    // max(Plds 65536, Wl 67584)
    unsigned short* Plds = (unsigned short*)smem;
    unsigned short (*Wl)[264] = (unsigned short (*)[264])smem;
    __shared__ float s_psq[256];

    const int t = threadIdx.x;
    const int w = t >> 6;          // wave 0..7
    const int l = t & 63;          // lane
    const int c = l & 15;
    const int g = l >> 4;
    const int myrow = w * 16 + c;  // this lane's token row within the tile
    const long base_tok = (long)blockIdx.x * 128;

    // ---- X bulk prefetch (per-lane rows, 2 float4 per k-tile) ----
    const float* xrow = X + (base_tok + myrow) * DIM;
    float4 xf[8];
    #pragma unroll
    for (int kt = 0; kt < 4; ++kt) {
        xf[kt * 2]     = *(const float4*)(xrow + kt * 32 + g * 8);
        xf[kt * 2 + 1] = *(const float4*)(xrow + kt * 32 + g * 8 + 4);
    }

    if (t < 256) s_psq[t] = psq[t];

    // ---- Stage PfH (64 KB) -> LDS: 64 chunks of 1 KB, 8 per wave ----
    #pragma unroll
    for (int i = 0; i < 8; ++i) {
        int q = w * 8 + i;
        __builtin_amdgcn_global_load_lds(
            (g_u32*)(PfH + q * 512 + l * 8),
            (l_u32*)(Plds + q * 512),
            16, 0, 0);
    }
    asm volatile("s_waitcnt vmcnt(0)" ::: "memory");
    __syncthreads();

    // ---- Convert X to bf16 hi/lo, accumulate x_sq ----
    bf16x8 xh[4], xl[4];
    float ps = 0.f;
    #pragma unroll
    for (int kt = 0; kt < 4; ++kt) {
        float xv[8] = {xf[kt*2].x, xf[kt*2].y, xf[kt*2].z, xf[kt*2].w,
                       xf[kt*2+1].x, xf[kt*2+1].y, xf[kt*2+1].z, xf[kt*2+1].w};
        #pragma unroll
        for (int j = 0; j < 8; ++j) {
            ps += xv[j] * xv[j];
            unsigned short h = f2bf(xv[j]);
            xh[kt][j] = (short)h;
            xl[kt][j] = (short)f2bf(xv[j] - bf2f(h));
        }
    }
    ps += __shfl_xor(ps, 16, 64);
    ps += __shfl_xor(ps, 32, 64);
    const float xq = ps;

    // ---- Phase 2: cross S^T = P @ X^T (A-frags from LDS) ----
    f32x4 acc[16];
    #pragma unroll
    for (int m = 0; m < 16; ++m) acc[m] = (f32x4){0.f, 0.f, 0.f, 0.f};

    #pragma unroll
    for (int kt = 0; kt < 4; ++kt) {
        #pragma unroll
        for (int m = 0; m < 16; ++m) {
            bf16x8 ah = *(const bf16x8*)&Plds[((kt * 16 + m) * 64 + l) * 8];
            acc[m] = __builtin_amdgcn_mfma_f32_16x16x32_bf16(ah, xh[kt], acc[m], 0, 0, 0);
            acc[m] = __builtin_amdgcn_mfma_f32_16x16x32_bf16(ah, xl[kt], acc[m], 0, 0, 0);
        }
    }

    // ---- Phase 3: softmax over protos ----
    float mx = -3.4e38f;
    #pragma unroll
    for (int m = 0; m < 16; ++m) {
        #pragma unroll
        for (int r = 0; r < 4; ++r) {
            int proto = m * 16 + g * 4 + r;
            float s2 = fmaxf(xq + s_psq[proto] - 2.f * acc[m][r], 0.f);
            float lg = -sqrtf(s2) * 2.5f;   // 1/T = 1/0.4
            acc[m][r] = lg;
            mx = fmaxf(mx, lg);
        }
    }
    mx = fmaxf(mx, __shfl_xor(mx, 16, 64));
    mx = fmaxf(mx, __shfl_xor(mx, 32, 64));
    float sum = 0.f;
    #pragma unroll
    for (int m = 0; m < 16; ++m) {
        #pragma unroll
        for (int r = 0; r < 4; ++r) {
            float p = __expf(acc[m][r] - mx);
            acc[m][r] = p;
            sum += p;
        }
    }
    sum += __shfl_xor(sum, 16, 64);
    sum += __shfl_xor(sum, 32, 64);
    const float inv = 1.0f / sum;

    // ---- Phase 4: W -> LDS (bf16, aliases Plds), coalesced f32 writes ----
    __syncthreads();   // all waves done reading Plds before overwrite
    #pragma unroll
    for (int m = 0; m < 16; ++m) {
        us4 wv = {f2bf(acc[m][0] * inv), f2bf(acc[m][1] * inv),
                  f2bf(acc[m][2] * inv), f2bf(acc[m][3] * inv)};
        *(us4*)&Wl[myrow][m * 16 + g * 4] = wv;
    }
    __syncthreads();

    {
        float* wout = weights + base_tok * M_PROTO;
        #pragma unroll
        for (int i = 0; i < 16; ++i) {
            int idx = i * 512 + t;
            int row = idx >> 6;
            int c4  = (idx & 63) * 4;
            us4 wv = *(const us4*)&Wl[row][c4];
            float4 o = {bf2f(wv[0]), bf2f(wv[1]), bf2f(wv[2]), bf2f(wv[3])};
            *(float4*)&wout[row * M_PROTO + c4] = o;
        }
    }

    // ---- Phase 5: blended = W @ P (K=256; wave w owns cols w*16..w*16+15) ----
    f32x4 acc2[8];
    #pragma unroll
    for (int m = 0; m < 8; ++m) acc2[m] = (f32x4){0.f, 0.f, 0.f, 0.f};

    const bf16x8* pth = (const bf16x8*)PTfH;
    const bf16x8* ptl = (const bf16x8*)PTfL;

    #pragma unroll
    for (int kt = 0; kt < 8; ++kt) {
        bf16x8 bh = pth[(kt * 8 + w) * 64 + l];
        bf16x8 bl = ptl[(kt * 8 + w) * 64 + l];
        #pragma unroll
        for (int m = 0; m < 8; ++m) {
            bf16x8 aw = *(const bf16x8*)&Wl[m * 16 + c][kt * 32 + g * 8];
            acc2[m] = __builtin_amdgcn_mfma_f32_16x16x32_bf16(aw, bh, acc2[m], 0, 0, 0);
            acc2[m] = __builtin_amdgcn_mfma_f32_16x16x32_bf16(aw, bl, acc2[m], 0, 0, 0);
        }
    }

    float* bout = blended + base_tok * DIM;
    #pragma unroll
    for (int m = 0; m < 8; ++m)
        #pragma unroll
        for (int r = 0; r < 4; ++r) {
            int row = m * 16 + g * 4 + r;
            int d   = w * 16 + c;
            bout[row * DIM + d] = acc2[m][r];
        }
}

extern "C" void kernel_launch(void* const* d_in, const int* in_sizes, int n_in,
                              void* d_out, int out_size, void* d_ws, size_t ws_size,
                              hipStream_t stream) {
    const float* x = (const float*)d_in[0];
    const float* protos = (const float*)d_in[1];

    float* out = (float*)d_out;
    float* blended = out;                               // [N,128]
    float* weights = out + (size_t)N_TOK * DIM;         // [N,256]

    unsigned short* PfH  = (unsigned short*)d_ws;       // 32768 elems each
    unsigned short* PTfH = PfH  + 32768;
    unsigned short* PTfL = PTfH + 32768;
    float*          psq  = (float*)(PTfL + 32768);      // 256 f32

    prep_kernel<<<M_PROTO, DIM, 0, stream>>>(protos, PfH, PTfH, PTfL, psq);
    softsom_main<<<N_TOK / 128, 512, 0, stream>>>(x, PfH, PTfH, PTfL, psq,
                                                  blended, weights);
}